// Round 5
// baseline (138.582 us; speedup 1.0000x reference)
//
#include <hip/hip_runtime.h>
#include <hip/hip_bf16.h>

// ---------------------------------------------------------------------------
// Diagonal-covariance GMM log-likelihoods as one bf16 MFMA GEMM + bias:
//   out[m,k] = sum_f [ x^2 * (-0.5/cov) + x * (mu/cov) ] + bias[k]
// GEMM: M=16384, N=512 (padded from 500), K2=2048 (interleaved x^2/x pairs)
//
// R4: latency-service fixes on top of R3 (which fixed the 16-way LDS conflict):
//  (a) Wb rows padded to 1056 dwords (4224 B = 33x128B). R3's B fragment loads
//      touched 16 rows at exactly 4 KB stride -> L2 channel camping; these
//      loads feed the MFMAs directly. Padding spreads rows across channels.
//  (b) BM 128->64: grid 1024 = 4 blocks/CU = 16 waves/CU (4/SIMD) for latency
//      hiding (R3 had 2/SIMD, Occupancy 21%).
//  (c) B loads issued immediately after the first barrier (head start over
//      the LDS-write + barrier phase).
// ---------------------------------------------------------------------------

typedef __attribute__((ext_vector_type(8))) __bf16 bf16x8;
typedef __attribute__((ext_vector_type(4))) float  f32x4;

#define LOG_2PI 1.837877066409345339082f

constexpr int M_TOT = 16384;   // B*T
constexpr int F_DIM = 1024;
constexpr int K_GMM = 500;
constexpr int N_PAD = 512;

constexpr int BM  = 64;
constexpr int BN  = 128;
constexpr int BKF = 32;              // K-step in floats (=> 64 bf16 along K2)
constexpr int NIT = F_DIM / BKF;     // 32 K-steps

constexpr int W_STRIDE_DW = 1056;    // padded W row stride in dwords (4224 B)

// pack (bf16(x*x), bf16(x)) into one dword: low16 = x^2 (even K2 slot), hi16 = x
__device__ __forceinline__ unsigned pack_sq_x(float x) {
    __hip_bfloat162 h = __float22bfloat162_rn(make_float2(x * x, x));
    union { __hip_bfloat162 h; unsigned u; } cv;
    cv.h = h;
    return cv.u;
}

// ---------------------------------------------------------------------------
// prep: W[k][2f] = bf16(-0.5/cov), W[k][2f+1] = bf16(mu/cov); bias[k] in fp32.
// Rows k in [500,512) are zeroed (padding), bias=0 there. Row stride sdw.
// ---------------------------------------------------------------------------
__global__ __launch_bounds__(256) void prep_w_kernel(
    const float* __restrict__ mu, const float* __restrict__ cov,
    unsigned* __restrict__ Wb, float* __restrict__ bias, int sdw)
{
    const int k = blockIdx.x;
    const int t = threadIdx.x;
    float sl = 0.f, sq = 0.f;
    if (k < K_GMM) {
        #pragma unroll
        for (int j = 0; j < 4; ++j) {
            const int f   = t + j * 256;
            const float c = cov[k * F_DIM + f];
            const float m = mu[k * F_DIM + f];
            const float ic = 1.0f / c;
            __hip_bfloat162 h = __float22bfloat162_rn(make_float2(-0.5f * ic, m * ic));
            union { __hip_bfloat162 h; unsigned u; } cv; cv.h = h;
            Wb[k * sdw + f] = cv.u;
            sl += logf(c);
            sq += m * m * ic;
        }
    } else {
        #pragma unroll
        for (int j = 0; j < 4; ++j) Wb[k * sdw + t + j * 256] = 0u;
    }
    #pragma unroll
    for (int off = 32; off > 0; off >>= 1) {
        sl += __shfl_down(sl, off, 64);
        sq += __shfl_down(sq, off, 64);
    }
    __shared__ float red[8];
    if ((t & 63) == 0) { red[(t >> 6) * 2] = sl; red[(t >> 6) * 2 + 1] = sq; }
    __syncthreads();
    if (t == 0) {
        const float SL = red[0] + red[2] + red[4] + red[6];
        const float SQ = red[1] + red[3] + red[5] + red[7];
        bias[k] = (k < K_GMM)
                ? (-0.5f * (F_DIM * LOG_2PI) - 0.5f * SL - 0.5f * SQ) : 0.f;
    }
}

// ---------------------------------------------------------------------------
// GEMM: 64x128 tile, 4 waves (2x2, each 32x64), mfma_f32_16x16x32_bf16.
// A: X fp32 -> regs -> (x^2,x) bf16 -> XOR-swizzled LDS (8KB).
// B: per-lane bf16x8 fragment loads straight from padded Wb (L2-resident).
// Grid 1024 (4 blocks/CU); n-siblings of an m-tile are 256 apart (same XCD).
// Epilogue: single-pass 32KB LDS transpose -> dense coalesced float4 rows.
// ---------------------------------------------------------------------------
__global__ __launch_bounds__(256, 4) void gemm_kernel(
    const float* __restrict__ X, const unsigned* __restrict__ Wb,
    const float* __restrict__ bias, float* __restrict__ out, int sdw)
{
    __shared__ __align__(16) char smem[32768];
    unsigned short* As = reinterpret_cast<unsigned short*>(smem); // swizzled [64][64] bf16, 8KB
    float*          ep = reinterpret_cast<float*>(smem);          // 64x128 fp32 epilogue, 32KB

    const int bid    = blockIdx.x;
    const int m_base = (bid & 255) * BM;
    const int n_base = (bid >> 8) * BN;

    const int tid  = threadIdx.x;
    const int lane = tid & 63;
    const int wv   = tid >> 6;
    const int wr   = (wv >> 1) * 32;    // wave row block (0/32)
    const int wc   = (wv & 1) * 64;     // wave col block (0/64)
    const int hi   = lane >> 4;         // 0..3
    const int lo   = lane & 15;

    const int sr = tid >> 2;            // staging row 0..63
    const int sc = tid & 3;             // staging chunk pair

    const float4* Xv = reinterpret_cast<const float4*>(X);     // X row = 256 float4
    const int     S8 = sdw >> 2;                               // bf16x8 per W row
    const bf16x8* Wf = reinterpret_cast<const bf16x8*>(Wb);

    // per-lane W row bases (it-invariant, hoisted)
    int wrow[4];
    #pragma unroll
    for (int b = 0; b < 4; ++b)
        wrow[b] = (n_base + wc + b * 16 + lo) * S8;

    f32x4 acc[2][4];
    #pragma unroll
    for (int a = 0; a < 2; ++a)
        #pragma unroll
        for (int b = 0; b < 4; ++b)
            acc[a][b] = (f32x4){0.f, 0.f, 0.f, 0.f};

    float4 a_reg[2];
    #pragma unroll
    for (int j = 0; j < 2; ++j)
        a_reg[j] = Xv[(m_base + sr) * (F_DIM / 4) + sc * 2 + j];

    const int lsw = lo & 7;   // lane-constant read swizzle

    for (int it = 0; it < NIT; ++it) {
        __syncthreads();   // previous iteration's LDS reads complete

        // B fragments straight from global (L2, padded stride): head start
        bf16x8 bq[8];
        #pragma unroll
        for (int b = 0; b < 4; ++b)
            #pragma unroll
            for (int c = 0; c < 2; ++c)
                bq[b * 2 + c] = Wf[wrow[b] + it * 8 + c * 4 + hi];

        #pragma unroll
        for (int j = 0; j < 2; ++j) {
            const int chunk = (sc * 2 + j) ^ (sr & 7);   // XOR swizzle
            const float4 av = a_reg[j];
            uint4 wa;
            wa.x = pack_sq_x(av.x);
            wa.y = pack_sq_x(av.y);
            wa.z = pack_sq_x(av.z);
            wa.w = pack_sq_x(av.w);
            *reinterpret_cast<uint4*>(&As[sr * 64 + chunk * 8]) = wa;
        }
        __syncthreads();   // staging visible

        if (it + 1 < NIT) {   // small prefetch (8 VGPRs)
            #pragma unroll
            for (int j = 0; j < 2; ++j)
                a_reg[j] = Xv[(m_base + sr) * (F_DIM / 4) + (it + 1) * 8 + sc * 2 + j];
        }

        #pragma unroll
        for (int c = 0; c < 2; ++c) {
            bf16x8 af[2];
            #pragma unroll
            for (int a = 0; a < 2; ++a) {
                const int row   = wr + a * 16 + lo;
                const int chunk = (c * 4 + hi) ^ lsw;    // <=2-way -> free
                af[a] = *reinterpret_cast<const bf16x8*>(&As[row * 64 + chunk * 8]);
            }
            #pragma unroll
            for (int a = 0; a < 2; ++a)
                #pragma unroll
                for (int b = 0; b < 4; ++b)
                    acc[a][b] = __builtin_amdgcn_mfma_f32_16x16x32_bf16(
                        af[a], bq[b * 2 + c], acc[a][b], 0, 0, 0);
        }
    }

    // ---- Epilogue: acc+bias -> 32KB LDS fp32 tile -> dense coalesced rows ----
    __syncthreads();   // all waves' last LDS reads done; smem becomes ep
    #pragma unroll
    for (int b = 0; b < 4; ++b) {
        const int col = wc + b * 16 + lo;
        const float bv = bias[n_base + col];
        #pragma unroll
        for (int a = 0; a < 2; ++a) {
            const int er = wr + a * 16 + hi * 4;  // D: col=lane&15, row=(lane>>4)*4+i
            #pragma unroll
            for (int i = 0; i < 4; ++i)
                ep[(er + i) * 128 + col] = acc[a][b][i] + bv;
        }
    }
    __syncthreads();

    const int ncols = (K_GMM - n_base < BN) ? (K_GMM - n_base) : BN;  // 128 or 116
    #pragma unroll
    for (int k = 0; k < 8; ++k) {
        const int f    = k * 256 + tid;   // float4 id in 64x32 grid
        const int row  = f >> 5;
        const int slot = f & 31;
        if (slot * 4 < ncols) {
            const float4 v = *reinterpret_cast<const float4*>(&ep[row * 128 + slot * 4]);
            *reinterpret_cast<float4*>(
                &out[(size_t)(m_base + row) * K_GMM + n_base + slot * 4]) = v;
        }
    }
}

extern "C" void kernel_launch(void* const* d_in, const int* in_sizes, int n_in,
                              void* d_out, int out_size, void* d_ws, size_t ws_size,
                              hipStream_t stream)
{
    (void)in_sizes; (void)n_in; (void)out_size;
    const float* X   = (const float*)d_in[0];
    const float* mu  = (const float*)d_in[1];
    const float* cov = (const float*)d_in[2];
    float* out = (float*)d_out;

    // padded layout if workspace allows, else fall back to dense rows
    const size_t need_padded = (size_t)N_PAD * W_STRIDE_DW * 4 + 4096;
    const int sdw = (ws_size >= need_padded) ? W_STRIDE_DW : F_DIM;

    unsigned* Wb   = (unsigned*)d_ws;
    float*    bias = (float*)((char*)d_ws + (size_t)N_PAD * sdw * 4);

    prep_w_kernel<<<dim3(N_PAD), dim3(256), 0, stream>>>(mu, cov, Wb, bias, sdw);
    gemm_kernel<<<dim3((M_TOT / BM) * (N_PAD / BN)), dim3(256), 0, stream>>>(X, Wb, bias, out, sdw);
}

// Round 7
// 57.818 us; speedup vs baseline: 2.3969x; 2.3969x over previous
//
#include <hip/hip_runtime.h>
#include <hip/hip_bf16.h>

// ---------------------------------------------------------------------------
// Diagonal-covariance GMM log-likelihoods as one bf16 MFMA GEMM + bias:
//   out[m,k] = sum_f [ x^2 * (-0.5/cov) + x * (mu/cov) ] + bias[k]
// GEMM: M=16384, N=512 (padded from 500), K2=2048 (interleaved x^2/x pairs)
//
// R6 = R5 with the compile fix: NO arrays of LDS pointers (hipcc rejects the
// addrspacecast static initializer). Buffer pointers are computed per
// iteration from smem + runtime offset.
//
// R5 design: pipeline restructure at R3's geometry (128x128, 512 blocks,
// (256,2)):
//  (a) W stored as a pre-swizzled tiled image: per (n_tile, K-step) a
//      contiguous 16KB block, XOR swizzle baked into memory layout.
//  (b) B staged via __builtin_amdgcn_global_load_lds width=16 (linear dest +
//      pre-swizzled source), issued ONE ITERATION AHEAD into a double buffer.
//  (c) A-loads for it+1 also issued before the MFMAs of it; converted and
//      written to the other A buffer after the MFMAs. Single barrier/iter.
//  R4 lessons: never raise launch_bounds min-waves (register strangle);
//  BM=64 thrashes per-XCD L2 with X panels (keep BM=128).
// ---------------------------------------------------------------------------

typedef __attribute__((ext_vector_type(8))) __bf16 bf16x8;
typedef __attribute__((ext_vector_type(4))) float  f32x4;

#define LOG_2PI 1.837877066409345339082f

constexpr int M_TOT = 16384;   // B*T
constexpr int F_DIM = 1024;
constexpr int K_GMM = 500;
constexpr int N_PAD = 512;

constexpr int BM  = 128;
constexpr int BN  = 128;
constexpr int BKF = 32;              // K-step in floats (=> 64 bf16 along K2)
constexpr int NIT = F_DIM / BKF;     // 32 K-steps

// async global->LDS, 16B per lane (dest = uniform base + lane*16 in HW)
__device__ __forceinline__ void gload_lds16(const void* g, void* l) {
    __builtin_amdgcn_global_load_lds(
        (const __attribute__((address_space(1))) unsigned*)g,
        (__attribute__((address_space(3))) unsigned*)l, 16, 0, 0);
}

// pack (bf16(x*x), bf16(x)) into one dword: low16 = x^2 (even K2 slot), hi16 = x
__device__ __forceinline__ unsigned pack_sq_x(float x) {
    __hip_bfloat162 h = __float22bfloat162_rn(make_float2(x * x, x));
    union { __hip_bfloat162 h; unsigned u; } cv;
    cv.h = h;
    return cv.u;
}

// ---------------------------------------------------------------------------
// prep: build the swizzled tiled W image + fp32 bias.
// Image layout: block (t,it) at dword offset (t*32+it)*4096 holds the LDS
// image for n_tile t, K-step it: row r (0..127), logical chunk cc (0..7 of
// 8 bf16) stored at chunk position cc ^ (r&7). Element f -> it=f>>5,
// cc=(f>>2)&7, dword q=f&3 holds (bf16(-0.5/cov), bf16(mu/cov)).
// Rows k in [500,512) zeroed; bias=0 there.
// ---------------------------------------------------------------------------
__global__ __launch_bounds__(256) void prep_w_kernel(
    const float* __restrict__ mu, const float* __restrict__ cov,
    unsigned* __restrict__ Wimg, float* __restrict__ bias)
{
    const int k = blockIdx.x;           // 0..511 (component row)
    const int t = threadIdx.x;
    const int r  = k & 127;
    const int tt = k >> 7;
    const int rsw = r & 7;
    float sl = 0.f, sq = 0.f;
    #pragma unroll
    for (int j = 0; j < 4; ++j) {
        const int f  = t + j * 256;
        const int it = f >> 5;
        const int cc = (f >> 2) & 7;
        const int q  = f & 3;
        const int dw = (tt * 32 + it) * 4096 + r * 32 + ((cc ^ rsw) << 2) + q;
        if (k < K_GMM) {
            const float c = cov[k * F_DIM + f];
            const float m = mu[k * F_DIM + f];
            const float ic = 1.0f / c;
            __hip_bfloat162 h = __float22bfloat162_rn(make_float2(-0.5f * ic, m * ic));
            union { __hip_bfloat162 h; unsigned u; } cv; cv.h = h;
            Wimg[dw] = cv.u;
            sl += logf(c);
            sq += m * m * ic;
        } else {
            Wimg[dw] = 0u;
        }
    }
    #pragma unroll
    for (int off = 32; off > 0; off >>= 1) {
        sl += __shfl_down(sl, off, 64);
        sq += __shfl_down(sq, off, 64);
    }
    __shared__ float red[8];
    if ((t & 63) == 0) { red[(t >> 6) * 2] = sl; red[(t >> 6) * 2 + 1] = sq; }
    __syncthreads();
    if (t == 0) {
        const float SL = red[0] + red[2] + red[4] + red[6];
        const float SQ = red[1] + red[3] + red[5] + red[7];
        bias[k] = (k < K_GMM)
                ? (-0.5f * (F_DIM * LOG_2PI) - 0.5f * SL - 0.5f * SQ) : 0.f;
    }
}

// ---------------------------------------------------------------------------
// GEMM: 128x128 tile, 4 waves (2x2, each 64x64), mfma_f32_16x16x32_bf16.
// Double-buffered LDS: A buffers at smem+{0,16K} (XOR-swizzled [128][64]
// bf16), B buffers at smem+{32K,48K} (DMA'd pre-swizzled image blocks).
// One barrier/iter; all staging for it+1 issued before the MFMAs of it.
// 512 blocks (2/CU); n-siblings of an m-tile are 128 apart in bid (same XCD).
// ---------------------------------------------------------------------------
__global__ __launch_bounds__(256, 2) void gemm_kernel(
    const float* __restrict__ X, const unsigned* __restrict__ Wimg,
    const float* __restrict__ bias, float* __restrict__ out)
{
    __shared__ __align__(16) char smem[65536];
    float* ep = reinterpret_cast<float*>(smem);   // 64x128 fp32 epilogue (32KB)

    const int bid    = blockIdx.x;
    const int m_base = (bid & 127) * BM;
    const int n_tile = bid >> 7;
    const int n_base = n_tile * BN;

    const int tid  = threadIdx.x;
    const int lane = tid & 63;
    const int wv   = tid >> 6;
    const int wr   = (wv >> 1) * 64;    // wave row block (0/64)
    const int wc   = (wv & 1) * 64;     // wave col block (0/64)
    const int hi   = lane >> 4;         // 0..3
    const int lo   = lane & 15;
    const int lsw  = lo & 7;            // lane-constant fragment read swizzle

    const int sr = tid >> 1;            // A staging row 0..127
    const int sh = tid & 1;             // staging half (chunks 0-3 / 4-7)

    const float4* Xv   = reinterpret_cast<const float4*>(X);   // X row = 256 float4
    const char*   Wimc = reinterpret_cast<const char*>(Wimg);

    f32x4 acc[4][4];
    #pragma unroll
    for (int a = 0; a < 4; ++a)
        #pragma unroll
        for (int b = 0; b < 4; ++b)
            acc[a][b] = (f32x4){0.f, 0.f, 0.f, 0.f};

    // ---- prologue: stage it=0 into buffer 0 ----
    {
        const char* g0 = Wimc + (size_t)(n_tile * 32 + 0) * 16384;
        #pragma unroll
        for (int i = 0; i < 4; ++i)
            gload_lds16(g0 + i * 4096 + wv * 1024 + lane * 16,
                        smem + 32768 + i * 4096 + wv * 1024);
        float4 a0[4];
        #pragma unroll
        for (int j = 0; j < 4; ++j)
            a0[j] = Xv[(m_base + sr) * (F_DIM / 4) + sh * 4 + j];
        unsigned short* A0 = reinterpret_cast<unsigned short*>(smem);
        #pragma unroll
        for (int j = 0; j < 4; ++j) {
            const int chunk = (sh * 4 + j) ^ (sr & 7);
            uint4 wa;
            wa.x = pack_sq_x(a0[j].x);
            wa.y = pack_sq_x(a0[j].y);
            wa.z = pack_sq_x(a0[j].z);
            wa.w = pack_sq_x(a0[j].w);
            *reinterpret_cast<uint4*>(&A0[sr * 64 + chunk * 8]) = wa;
        }
    }
    __syncthreads();   // drains DMA (vmcnt) + LDS writes

    for (int it = 0; it < NIT; ++it) {
        const int cur = it & 1;
        const int nxt = cur ^ 1;
        const unsigned short* Asc =
            reinterpret_cast<const unsigned short*>(smem + cur * 16384);
        const unsigned short* Bsc =
            reinterpret_cast<const unsigned short*>(smem + 32768 + cur * 16384);
        char*           Bdst = smem + 32768 + nxt * 16384;
        unsigned short* Adst = reinterpret_cast<unsigned short*>(smem + nxt * 16384);

        float4 a_next[4];
        if (it + 1 < NIT) {
            // B DMA for it+1 (async into Bdst) — a full MFMA phase to land
            const char* gs = Wimc + (size_t)(n_tile * 32 + it + 1) * 16384;
            #pragma unroll
            for (int i = 0; i < 4; ++i)
                gload_lds16(gs + i * 4096 + wv * 1024 + lane * 16,
                            Bdst + i * 4096 + wv * 1024);
            // A loads for it+1
            #pragma unroll
            for (int j = 0; j < 4; ++j)
                a_next[j] = Xv[(m_base + sr) * (F_DIM / 4) + (it + 1) * 8 + sh * 4 + j];
        }

        // ---- MFMAs on buffer cur ----
        #pragma unroll
        for (int c = 0; c < 2; ++c) {
            bf16x8 af[4], bf[4];
            #pragma unroll
            for (int a = 0; a < 4; ++a) {
                const int row   = wr + a * 16 + lo;
                const int chunk = (c * 4 + hi) ^ lsw;
                af[a] = *reinterpret_cast<const bf16x8*>(&Asc[row * 64 + chunk * 8]);
            }
            #pragma unroll
            for (int b = 0; b < 4; ++b) {
                const int row   = wc + b * 16 + lo;
                const int chunk = (c * 4 + hi) ^ lsw;
                bf[b] = *reinterpret_cast<const bf16x8*>(&Bsc[row * 64 + chunk * 8]);
            }
            #pragma unroll
            for (int a = 0; a < 4; ++a)
                #pragma unroll
                for (int b = 0; b < 4; ++b)
                    acc[a][b] = __builtin_amdgcn_mfma_f32_16x16x32_bf16(
                        af[a], bf[b], acc[a][b], 0, 0, 0);
        }

        if (it + 1 < NIT) {
            // convert + write A for it+1 (loads had the MFMA phase to land)
            #pragma unroll
            for (int j = 0; j < 4; ++j) {
                const int chunk = (sh * 4 + j) ^ (sr & 7);
                uint4 wa;
                wa.x = pack_sq_x(a_next[j].x);
                wa.y = pack_sq_x(a_next[j].y);
                wa.z = pack_sq_x(a_next[j].z);
                wa.w = pack_sq_x(a_next[j].w);
                *reinterpret_cast<uint4*>(&Adst[sr * 64 + chunk * 8]) = wa;
            }
        }
        __syncthreads();   // next-iter buffers ready; cur buffers free
    }

    // ---- Epilogue: two 64-row passes; acc+bias -> LDS -> dense row writes ----
    const int ncols = (K_GMM - n_base < BN) ? (K_GMM - n_base) : BN;  // 128 or 116
    #pragma unroll
    for (int p = 0; p < 2; ++p) {
        __syncthreads();               // previous LDS use done
        if ((wv >> 1) == p) {          // the 2 waves owning row-half p dump acc
            #pragma unroll
            for (int b = 0; b < 4; ++b) {
                const int col = wc + b * 16 + lo;
                const float bv = bias[n_base + col];
                #pragma unroll
                for (int a = 0; a < 4; ++a)
                    #pragma unroll
                    for (int i = 0; i < 4; ++i)
                        ep[(a * 16 + hi * 4 + i) * 128 + col] = acc[a][b][i] + bv;
            }
        }
        __syncthreads();
        #pragma unroll
        for (int k = 0; k < 8; ++k) {
            const int f    = k * 256 + tid;   // float4 id in 64x32 grid
            const int row  = f >> 5;
            const int slot = f & 31;
            if (slot * 4 < ncols) {
                const float4 v = *reinterpret_cast<const float4*>(&ep[row * 128 + slot * 4]);
                *reinterpret_cast<float4*>(
                    &out[(size_t)(m_base + p * 64 + row) * K_GMM + n_base + slot * 4]) = v;
            }
        }
    }
}

extern "C" void kernel_launch(void* const* d_in, const int* in_sizes, int n_in,
                              void* d_out, int out_size, void* d_ws, size_t ws_size,
                              hipStream_t stream)
{
    (void)in_sizes; (void)n_in; (void)out_size; (void)ws_size;
    const float* X   = (const float*)d_in[0];
    const float* mu  = (const float*)d_in[1];
    const float* cov = (const float*)d_in[2];
    float* out = (float*)d_out;

    // workspace: W image = 512*1024 dwords (2 MiB), then bias[512] f32
    unsigned* Wimg = (unsigned*)d_ws;
    float*    bias = (float*)((char*)d_ws + (size_t)N_PAD * F_DIM * 4);

    prep_w_kernel<<<dim3(N_PAD), dim3(256), 0, stream>>>(mu, cov, Wimg, bias);
    gemm_kernel<<<dim3((M_TOT / BM) * (N_PAD / BN)), dim3(256), 0, stream>>>(X, Wimg, bias, out);
}